// Round 1
// baseline (152.602 us; speedup 1.0000x reference)
//
#include <hip/hip_runtime.h>

// GCN aggregator: out[r,:] = relu( (1/25 * sum_s F[idx[r,s],:]) @ W )
// r in [0, 32768), D_IN = D_OUT = 128, S = 25.
//
// Fused single kernel:
//  - W (128x128 fp32 = 64 KB) staged in LDS once per block (amortized over 16 rows)
//  - gather-mean with 50 independent loads in flight per thread (L3-latency hiding)
//  - matmul: 2 rows share each sW read; stride-1 lane access = bank-conflict-free

#define DEG 25
#define DIM 128
#define ROWS_PER_BLOCK 16
#define BLOCK 256

__global__ __launch_bounds__(BLOCK, 2) void gcn_fused(
    const float* __restrict__ F,    // [N_NODES, 128]
    const int*   __restrict__ idx,  // [n_rows, 25]
    const float* __restrict__ W,    // [128, 128]
    float*       __restrict__ out,  // [n_rows, 128]
    int n_rows)
{
    __shared__ float sW[DIM * DIM];   // 64 KB
    __shared__ float sV[4 * DIM];     // 4 row-vectors in flight

    const int tid = threadIdx.x;

    // ---- stage W into LDS, float4-coalesced: 4096 float4 / 256 threads = 16 each
    {
        const float4* W4 = (const float4*)W;
        float4* sW4 = (float4*)sW;
#pragma unroll
        for (int i = 0; i < 16; ++i)
            sW4[i * BLOCK + tid] = W4[i * BLOCK + tid];
    }
    __syncthreads();

    const int half = tid >> 7;        // 0 or 1: which row-pair this thread serves
    const int lane = tid & 127;       // feature / output column
    const int row0 = blockIdx.x * ROWS_PER_BLOCK;

    for (int p = 0; p < ROWS_PER_BLOCK; p += 4) {
        const int rA = row0 + p + half * 2;
        const int rB = rA + 1;

        // ---- prefetch all 50 indices (register-resident -> 50 independent F loads)
        const int* ipA = idx + rA * DEG;
        const int* ipB = idx + rB * DEG;
        int jA[DEG], jB[DEG];
#pragma unroll
        for (int s = 0; s < DEG; ++s) jA[s] = ipA[s];
#pragma unroll
        for (int s = 0; s < DEG; ++s) jB[s] = ipB[s];

        // ---- gather + mean (each thread owns one feature column)
        float a0 = 0.f, a1 = 0.f;
#pragma unroll
        for (int s = 0; s < DEG; ++s) a0 += F[(size_t)jA[s] * DIM + lane];
#pragma unroll
        for (int s = 0; s < DEG; ++s) a1 += F[(size_t)jB[s] * DIM + lane];

        sV[(half * 2 + 0) * DIM + lane] = a0 * (1.0f / 25.0f);
        sV[(half * 2 + 1) * DIM + lane] = a1 * (1.0f / 25.0f);
        __syncthreads();

        // ---- matmul: out[r][lane] = relu(sum_d v[d] * W[d][lane])
        // sW read: lanes stride-1 (2 lanes/bank = free); v reads are wave-uniform broadcasts.
        // Two rows per thread share each sW load.
        const float* vA = &sV[(half * 2) * DIM];
        const float* vB = vA + DIM;
        float s0 = 0.f, s1 = 0.f;
#pragma unroll 8
        for (int d = 0; d < DIM; ++d) {
            const float w = sW[d * DIM + lane];
            s0 += vA[d] * w;
            s1 += vB[d] * w;
        }
        out[(size_t)rA * DIM + lane] = fmaxf(s0, 0.f);
        out[(size_t)rB * DIM + lane] = fmaxf(s1, 0.f);
        __syncthreads();   // before next group overwrites sV
    }
}

extern "C" void kernel_launch(void* const* d_in, const int* in_sizes, int n_in,
                              void* d_out, int out_size, void* d_ws, size_t ws_size,
                              hipStream_t stream) {
    const float* F   = (const float*)d_in[0];   // features [100000,128] fp32
    const int*   idx = (const int*)d_in[1];     // sample_res [8,4096,25] -> int32
    const float* W   = (const float*)d_in[2];   // weights [128,128] fp32
    float* out = (float*)d_out;                 // [8,4096,128] fp32

    const int n_rows = in_sizes[1] / DEG;       // 32768
    const int grid = n_rows / ROWS_PER_BLOCK;   // 2048
    gcn_fused<<<grid, BLOCK, 0, stream>>>(F, idx, W, out, n_rows);
}

// Round 2
// 143.206 us; speedup vs baseline: 1.0656x; 1.0656x over previous
//
#include <hip/hip_runtime.h>

// GCN aggregator: out[r,:] = relu( (1/25 * sum_s F[idx[r,s],:]) @ W )
// r in [0, 32768), D_IN = D_OUT = 128, S = 25.
//
// Round 2: kill the LDS-scalar matmul + raise occupancy.
//  - W is NOT staged in LDS (64 KB killed occupancy; W is L2-resident anyway).
//    Matmul reads W via float4 from global: 64 KB distinct/block ~= 134 MB L2 total.
//  - LDS only holds mean vectors (8 KB) + block indices (1.6 KB) -> 4 blocks/CU.
//  - float4 throughout: gather is 25 dwordx4/row, matmul inner loop is
//    2 ds_read_b128 (broadcast) + 4 global dwordx4 + 32 FMA per 4 d's.

#define DEG 25
#define DIM 128
#define RPB 16            // rows per block
#define BLOCK 256
#define CG 32             // float4 groups per 128-wide row

__device__ __forceinline__ float4 relu4(float4 v) {
    return make_float4(fmaxf(v.x, 0.f), fmaxf(v.y, 0.f),
                       fmaxf(v.z, 0.f), fmaxf(v.w, 0.f));
}

__global__ __launch_bounds__(BLOCK, 4) void gcn_fused(
    const float* __restrict__ F,    // [N_NODES, 128]
    const int*   __restrict__ idx,  // [n_rows, 25]
    const float* __restrict__ W,    // [128, 128]
    float*       __restrict__ out,  // [n_rows, 128]
    int n_rows)
{
    __shared__ float4 sV[RPB * CG];     // 8 KB: mean vectors
    __shared__ int    sIdx[RPB * DEG];  // 1.6 KB: this block's indices

    const float4* F4   = (const float4*)F;
    const float4* W4   = (const float4*)W;
    float4*       out4 = (float4*)out;

    const int tid  = threadIdx.x;
    const int row0 = blockIdx.x * RPB;

    // ---- stage this block's 400 indices (coalesced, once)
    for (int i = tid; i < RPB * DEG; i += BLOCK)
        sIdx[i] = idx[(size_t)row0 * DEG + i];
    __syncthreads();

    const int cg = tid & 31;   // which float4 of the row
    const int rs = tid >> 5;   // row slot 0..7 (handles rows rs and rs+8)

    // ---- gather + mean: 25 independent dwordx4 loads per row
#pragma unroll
    for (int rr = 0; rr < 2; ++rr) {
        const int r = rs + rr * 8;
        int j[DEG];
#pragma unroll
        for (int s = 0; s < DEG; ++s) j[s] = sIdx[r * DEG + s];  // LDS broadcast
        float4 acc = make_float4(0.f, 0.f, 0.f, 0.f);
#pragma unroll
        for (int s = 0; s < DEG; ++s) {
            float4 f = F4[(size_t)j[s] * CG + cg];
            acc.x += f.x; acc.y += f.y; acc.z += f.z; acc.w += f.w;
        }
        const float inv = 1.0f / 25.0f;
        acc.x *= inv; acc.y *= inv; acc.z *= inv; acc.w *= inv;
        sV[r * CG + cg] = acc;
    }
    __syncthreads();

    // ---- matmul + relu: thread computes rows {rs, rs+8} x cols [4cg, 4cg+4)
    // v reads are wave-broadcast ds_read_b128; W reads are contiguous 512 B
    // per half-wave, L1/L2-resident.
    const float4* vA = &sV[rs * CG];
    const float4* vB = &sV[(rs + 8) * CG];
    float4 o0 = make_float4(0.f, 0.f, 0.f, 0.f);
    float4 o1 = make_float4(0.f, 0.f, 0.f, 0.f);
#pragma unroll 4
    for (int d4 = 0; d4 < CG; ++d4) {
        const float4 a = vA[d4];
        const float4 b = vB[d4];
        const float4 w0 = W4[(size_t)(4 * d4 + 0) * CG + cg];
        const float4 w1 = W4[(size_t)(4 * d4 + 1) * CG + cg];
        const float4 w2 = W4[(size_t)(4 * d4 + 2) * CG + cg];
        const float4 w3 = W4[(size_t)(4 * d4 + 3) * CG + cg];

        o0.x += a.x * w0.x; o0.y += a.x * w0.y; o0.z += a.x * w0.z; o0.w += a.x * w0.w;
        o0.x += a.y * w1.x; o0.y += a.y * w1.y; o0.z += a.y * w1.z; o0.w += a.y * w1.w;
        o0.x += a.z * w2.x; o0.y += a.z * w2.y; o0.z += a.z * w2.z; o0.w += a.z * w2.w;
        o0.x += a.w * w3.x; o0.y += a.w * w3.y; o0.z += a.w * w3.z; o0.w += a.w * w3.w;

        o1.x += b.x * w0.x; o1.y += b.x * w0.y; o1.z += b.x * w0.z; o1.w += b.x * w0.w;
        o1.x += b.y * w1.x; o1.y += b.y * w1.y; o1.z += b.y * w1.z; o1.w += b.y * w1.w;
        o1.x += b.z * w2.x; o1.y += b.z * w2.y; o1.z += b.z * w2.z; o1.w += b.z * w2.w;
        o1.x += b.w * w3.x; o1.y += b.w * w3.y; o1.z += b.w * w3.z; o1.w += b.w * w3.w;
    }

    out4[(size_t)(row0 + rs) * CG + cg]     = relu4(o0);
    out4[(size_t)(row0 + rs + 8) * CG + cg] = relu4(o1);
}

extern "C" void kernel_launch(void* const* d_in, const int* in_sizes, int n_in,
                              void* d_out, int out_size, void* d_ws, size_t ws_size,
                              hipStream_t stream) {
    const float* F   = (const float*)d_in[0];   // features [100000,128] fp32
    const int*   idx = (const int*)d_in[1];     // sample_res [8,4096,25] int32
    const float* W   = (const float*)d_in[2];   // weights [128,128] fp32
    float* out = (float*)d_out;                 // [8,4096,128] fp32

    const int n_rows = in_sizes[1] / DEG;       // 32768
    const int grid = n_rows / RPB;              // 2048
    gcn_fused<<<grid, BLOCK, 0, stream>>>(F, idx, W, out, n_rows);
}

// Round 3
// 133.877 us; speedup vs baseline: 1.1399x; 1.0697x over previous
//
#include <hip/hip_runtime.h>

// GCN aggregator: out[r,:] = relu( (1/25 * sum_s F[idx[r,s],:]) @ W )
// r in [0, 32768), D_IN = D_OUT = 128, S = 25.
//
// Round 3: commute the linear ops. mean(gather(F)) @ W == mean(gather(F @ W)).
//  Kernel 1: G = bf16(F @ W)  (MFMA 16x16x32 bf16, fp32 accum) -> d_ws
//  Kernel 2: out = relu(mean_s G[idx[r,s]])  (bf16 gather halves the 419 MB
//            gather demand to 210 MB; table shrinks 51.2 -> 25.6 MB => better
//            L2 residency)
// Fallback to the round-2 fused kernel if ws_size is too small for G.

#define DEG 25
#define DIM 128

typedef __attribute__((ext_vector_type(8))) short short8;   // 8 bf16 = 4 VGPR
typedef __attribute__((ext_vector_type(4))) float floatx4;  // MFMA acc

__device__ __forceinline__ unsigned short f2bf(float f) {
    // round-to-nearest-even fp32 -> bf16 (inputs finite; no NaN handling needed)
    unsigned u = __float_as_uint(f);
    return (unsigned short)((u + 0x7fffu + ((u >> 16) & 1u)) >> 16);
}

// ---------------------------------------------------------------- GEMM ------
// G[M,128] = bf16( A[M,128] @ B[128,128] ), block = 128 rows x 128 cols,
// 4 waves, each wave does 32 rows x 128 cols with 16x16x32 bf16 MFMA.
// B lives transposed in LDS (stride 136 bf16 -> uniform bank distribution);
// A-fragments load straight from global (each element read exactly once).
#define BSTRIDE 136

__global__ __launch_bounds__(256, 2) void gemm_fw(
    const float* __restrict__ A,       // [M,128] fp32
    const float* __restrict__ B,       // [128,128] fp32
    unsigned short* __restrict__ G,    // [M,128] bf16 out
    int M)
{
    __shared__ unsigned short sBt[DIM * BSTRIDE];  // B^T [n][k], 34.8 KB

    const int tid = threadIdx.x;

    // ---- stage B transposed, with fp32->bf16 convert (one-time per block)
    {
        const float4* B4 = (const float4*)B;
#pragma unroll
        for (int i = 0; i < 16; ++i) {
            const int linear = i * 256 + tid;   // 0..4095 float4s
            const int k  = linear >> 5;         // B row
            const int c4 = linear & 31;         // which float4 in the row
            const float4 v = B4[linear];
            const int n = c4 * 4;
            sBt[(n + 0) * BSTRIDE + k] = f2bf(v.x);
            sBt[(n + 1) * BSTRIDE + k] = f2bf(v.y);
            sBt[(n + 2) * BSTRIDE + k] = f2bf(v.z);
            sBt[(n + 3) * BSTRIDE + k] = f2bf(v.w);
        }
    }
    __syncthreads();

    const int wave = tid >> 6;
    const int lane = tid & 63;
    const int quad = lane >> 4;    // 0..3
    const int l16  = lane & 15;

    const int rw0 = blockIdx.x * 128 + wave * 32;   // this wave's first row

    floatx4 acc[2][8];
#pragma unroll
    for (int mt = 0; mt < 2; ++mt)
#pragma unroll
        for (int nt = 0; nt < 8; ++nt)
            acc[mt][nt] = (floatx4){0.f, 0.f, 0.f, 0.f};

#pragma unroll
    for (int kt = 0; kt < 4; ++kt) {
        const int k0 = kt * 32;

        // A-frags: lane holds A[m = l16][k = k0 + quad*8 + j], j=0..7
        short8 afrag[2];
#pragma unroll
        for (int mt = 0; mt < 2; ++mt) {
            int row = rw0 + mt * 16 + l16;
            if (row >= M) row = M - 1;          // tail clamp (stores guarded)
            const float* ap = A + (size_t)row * DIM + k0 + quad * 8;
            const float4 x = *(const float4*)ap;
            const float4 y = *(const float4*)(ap + 4);
            unsigned p0 = (unsigned)f2bf(x.x) | ((unsigned)f2bf(x.y) << 16);
            unsigned p1 = (unsigned)f2bf(x.z) | ((unsigned)f2bf(x.w) << 16);
            unsigned p2 = (unsigned)f2bf(y.x) | ((unsigned)f2bf(y.y) << 16);
            unsigned p3 = (unsigned)f2bf(y.z) | ((unsigned)f2bf(y.w) << 16);
            uint4 packed = make_uint4(p0, p1, p2, p3);
            afrag[mt] = __builtin_bit_cast(short8, packed);
        }

        // B-frags from LDS: lane holds B[k = k0+quad*8+j][n = nt*16 + l16]
#pragma unroll
        for (int nt = 0; nt < 8; ++nt) {
            const uint4 u = *(const uint4*)&sBt[(nt * 16 + l16) * BSTRIDE + k0 + quad * 8];
            const short8 bfrag = __builtin_bit_cast(short8, u);
#pragma unroll
            for (int mt = 0; mt < 2; ++mt)
                acc[mt][nt] = __builtin_amdgcn_mfma_f32_16x16x32_bf16(
                    afrag[mt], bfrag, acc[mt][nt], 0, 0, 0);
        }
    }

    // ---- store: D elem r of lane = (row quad*4+r, col l16) within tile
#pragma unroll
    for (int mt = 0; mt < 2; ++mt)
#pragma unroll
        for (int nt = 0; nt < 8; ++nt)
#pragma unroll
            for (int r = 0; r < 4; ++r) {
                const int row = rw0 + mt * 16 + quad * 4 + r;
                if (row < M)
                    G[(size_t)row * DIM + nt * 16 + l16] = f2bf(acc[mt][nt][r]);
            }
}

// ------------------------------------------------------- gather-mean-relu ---
// out[r,:] = relu( 1/25 * sum_s G[idx[r,s],:] )   G rows are 256 B bf16.
// 16-lane group per row; each lane owns 8 consecutive cols (one uint4 load
// per neighbor). 25 independent loads in flight per row for latency hiding.
#define GRPB 32

__global__ __launch_bounds__(256, 4) void gather_mean_relu(
    const unsigned short* __restrict__ G,   // [n_nodes,128] bf16
    const int* __restrict__ idx,            // [n_rows,25]
    float* __restrict__ out,                // [n_rows,128] fp32
    int n_rows)
{
    __shared__ int sIdx[GRPB * DEG];

    const int tid  = threadIdx.x;
    const int row0 = blockIdx.x * GRPB;

    for (int i = tid; i < GRPB * DEG; i += 256)
        sIdx[i] = idx[(size_t)row0 * DEG + i];
    __syncthreads();

    const int grp = tid >> 4;   // 0..15
    const int l16 = tid & 15;   // which 16 B chunk of the 256 B row
    const uint4* G4 = (const uint4*)G;      // 16 uint4 per row
    float4* out4 = (float4*)out;

#pragma unroll
    for (int rr = 0; rr < 2; ++rr) {
        const int r = grp + rr * 16;

        uint4 v[DEG];
#pragma unroll
        for (int s = 0; s < DEG; ++s)
            v[s] = G4[(size_t)sIdx[r * DEG + s] * 16 + l16];

        float a0 = 0.f, a1 = 0.f, a2 = 0.f, a3 = 0.f;
        float a4 = 0.f, a5 = 0.f, a6 = 0.f, a7 = 0.f;
#pragma unroll
        for (int s = 0; s < DEG; ++s) {
            a0 += __uint_as_float(v[s].x << 16);
            a1 += __uint_as_float(v[s].x & 0xffff0000u);
            a2 += __uint_as_float(v[s].y << 16);
            a3 += __uint_as_float(v[s].y & 0xffff0000u);
            a4 += __uint_as_float(v[s].z << 16);
            a5 += __uint_as_float(v[s].z & 0xffff0000u);
            a6 += __uint_as_float(v[s].w << 16);
            a7 += __uint_as_float(v[s].w & 0xffff0000u);
        }
        const float inv = 1.0f / 25.0f;
        float4 o0 = make_float4(fmaxf(a0 * inv, 0.f), fmaxf(a1 * inv, 0.f),
                                fmaxf(a2 * inv, 0.f), fmaxf(a3 * inv, 0.f));
        float4 o1 = make_float4(fmaxf(a4 * inv, 0.f), fmaxf(a5 * inv, 0.f),
                                fmaxf(a6 * inv, 0.f), fmaxf(a7 * inv, 0.f));
        const size_t ob = (size_t)(row0 + r) * 32 + l16 * 2;
        out4[ob]     = o0;
        out4[ob + 1] = o1;
    }
}

// --------------------------------------------- fallback (round-2 kernel) ----
#define RPB 16
#define CG 32

__device__ __forceinline__ float4 relu4(float4 v) {
    return make_float4(fmaxf(v.x, 0.f), fmaxf(v.y, 0.f),
                       fmaxf(v.z, 0.f), fmaxf(v.w, 0.f));
}

__global__ __launch_bounds__(256, 4) void gcn_fused(
    const float* __restrict__ F, const int* __restrict__ idx,
    const float* __restrict__ W, float* __restrict__ out, int n_rows)
{
    __shared__ float4 sV[RPB * CG];
    __shared__ int    sIdx[RPB * DEG];

    const float4* F4 = (const float4*)F;
    const float4* W4 = (const float4*)W;
    float4* out4 = (float4*)out;

    const int tid = threadIdx.x;
    const int row0 = blockIdx.x * RPB;

    for (int i = tid; i < RPB * DEG; i += 256)
        sIdx[i] = idx[(size_t)row0 * DEG + i];
    __syncthreads();

    const int cg = tid & 31;
    const int rs = tid >> 5;

#pragma unroll
    for (int rr = 0; rr < 2; ++rr) {
        const int r = rs + rr * 8;
        int j[DEG];
#pragma unroll
        for (int s = 0; s < DEG; ++s) j[s] = sIdx[r * DEG + s];
        float4 acc = make_float4(0.f, 0.f, 0.f, 0.f);
#pragma unroll
        for (int s = 0; s < DEG; ++s) {
            float4 f = F4[(size_t)j[s] * CG + cg];
            acc.x += f.x; acc.y += f.y; acc.z += f.z; acc.w += f.w;
        }
        const float inv = 1.0f / 25.0f;
        acc.x *= inv; acc.y *= inv; acc.z *= inv; acc.w *= inv;
        sV[r * CG + cg] = acc;
    }
    __syncthreads();

    const float4* vA = &sV[rs * CG];
    const float4* vB = vA + DIM / 4 * 0 + 8 * CG;  // rows rs and rs+8
    float4 o0 = make_float4(0.f, 0.f, 0.f, 0.f);
    float4 o1 = make_float4(0.f, 0.f, 0.f, 0.f);
#pragma unroll 4
    for (int d4 = 0; d4 < CG; ++d4) {
        const float4 a = vA[d4];
        const float4 b = vB[d4];
        const float4 w0 = W4[(size_t)(4 * d4 + 0) * CG + cg];
        const float4 w1 = W4[(size_t)(4 * d4 + 1) * CG + cg];
        const float4 w2 = W4[(size_t)(4 * d4 + 2) * CG + cg];
        const float4 w3 = W4[(size_t)(4 * d4 + 3) * CG + cg];
        o0.x += a.x*w0.x + a.y*w1.x + a.z*w2.x + a.w*w3.x;
        o0.y += a.x*w0.y + a.y*w1.y + a.z*w2.y + a.w*w3.y;
        o0.z += a.x*w0.z + a.y*w1.z + a.z*w2.z + a.w*w3.z;
        o0.w += a.x*w0.w + a.y*w1.w + a.z*w2.w + a.w*w3.w;
        o1.x += b.x*w0.x + b.y*w1.x + b.z*w2.x + b.w*w3.x;
        o1.y += b.x*w0.y + b.y*w1.y + b.z*w2.y + b.w*w3.y;
        o1.z += b.x*w0.z + b.y*w1.z + b.z*w2.z + b.w*w3.z;
        o1.w += b.x*w0.w + b.y*w1.w + b.z*w2.w + b.w*w3.w;
    }
    out4[(size_t)(row0 + rs) * CG + cg]     = relu4(o0);
    out4[(size_t)(row0 + rs + 8) * CG + cg] = relu4(o1);
}

// ----------------------------------------------------------------------------
extern "C" void kernel_launch(void* const* d_in, const int* in_sizes, int n_in,
                              void* d_out, int out_size, void* d_ws, size_t ws_size,
                              hipStream_t stream) {
    const float* F   = (const float*)d_in[0];   // features [100000,128] fp32
    const int*   idx = (const int*)d_in[1];     // sample_res [8,4096,25] int32
    const float* W   = (const float*)d_in[2];   // weights [128,128] fp32
    float* out = (float*)d_out;                 // [8,4096,128] fp32

    const int n_nodes = in_sizes[0] / DIM;      // 100000
    const int n_rows  = in_sizes[1] / DEG;      // 32768

    const size_t need = (size_t)n_nodes * DIM * sizeof(unsigned short);
    if (ws_size >= need) {
        unsigned short* G = (unsigned short*)d_ws;
        gemm_fw<<<(n_nodes + 127) / 128, 256, 0, stream>>>(F, W, G, n_nodes);
        gather_mean_relu<<<n_rows / GRPB, 256, 0, stream>>>(G, idx, out, n_rows);
    } else {
        gcn_fused<<<n_rows / RPB, 256, 0, stream>>>(F, idx, W, out, n_rows);
    }
}

// Round 4
// 130.149 us; speedup vs baseline: 1.1725x; 1.0286x over previous
//
#include <hip/hip_runtime.h>

// GCN aggregator: out[r,:] = relu( (1/25 * sum_s F[idx[r,s],:]) @ W )
// r in [0, 32768), D_IN = D_OUT = 128, S = 25.
//
// Round 4: mean(gather(F)) @ W == mean(gather(F @ W)) (all linear), with a
// PERMUTED scratch layout so both producer and consumer stay vectorized:
//  Kernel 1: G = bf16(F @ W) via MFMA; G row position p = l16*8+nt holds
//            col 16*nt+l16  =>  each lane's 8 C-frag values for one row are
//            contiguous 16 B => dwordx4 stores (wave writes 4 full rows/inst).
//            (Round 3 used 64 scalar 2 B stores/lane here — the slack.)
//  Kernel 2: out = relu(mean_s G[idx[r,s]]) — loads unchanged (uint4/row-chunk);
//            out stores become 8 scalar fp32/lane, but group-lanes cover 16
//            consecutive cols => contiguous 64 B runs.

#define DEG 25
#define DIM 128

typedef __attribute__((ext_vector_type(8))) short short8;   // 8 bf16 = 4 VGPR
typedef __attribute__((ext_vector_type(4))) float floatx4;  // MFMA acc

__device__ __forceinline__ unsigned short f2bf(float f) {
    // round-to-nearest-even fp32 -> bf16 (inputs finite)
    unsigned u = __float_as_uint(f);
    return (unsigned short)((u + 0x7fffu + ((u >> 16) & 1u)) >> 16);
}

// ---------------------------------------------------------------- GEMM ------
// G[M,128] = bf16( A[M,128] @ B[128,128] ), 128-row blocks, 4 waves,
// each wave: 32 rows x 128 cols via 16x16x32 bf16 MFMA.
#define BSTRIDE 136

__global__ __launch_bounds__(256, 2) void gemm_fw(
    const float* __restrict__ A,       // [M,128] fp32
    const float* __restrict__ B,       // [128,128] fp32
    unsigned short* __restrict__ G,    // [M,128] bf16, PERMUTED rows
    int M)
{
    __shared__ unsigned short sBt[DIM * BSTRIDE];  // B^T [n][k], 34.8 KB

    const int tid = threadIdx.x;

    // ---- stage B transposed with fp32->bf16 (once per block)
    {
        const float4* B4 = (const float4*)B;
#pragma unroll
        for (int i = 0; i < 16; ++i) {
            const int linear = i * 256 + tid;   // 0..4095 float4s
            const int k  = linear >> 5;         // B row
            const int c4 = linear & 31;         // float4 within row
            const float4 v = B4[linear];
            const int n = c4 * 4;
            sBt[(n + 0) * BSTRIDE + k] = f2bf(v.x);
            sBt[(n + 1) * BSTRIDE + k] = f2bf(v.y);
            sBt[(n + 2) * BSTRIDE + k] = f2bf(v.z);
            sBt[(n + 3) * BSTRIDE + k] = f2bf(v.w);
        }
    }
    __syncthreads();

    const int wave = tid >> 6;
    const int lane = tid & 63;
    const int quad = lane >> 4;    // 0..3
    const int l16  = lane & 15;

    const int rw0 = blockIdx.x * 128 + wave * 32;   // wave's first row

    floatx4 acc[2][8];
#pragma unroll
    for (int mt = 0; mt < 2; ++mt)
#pragma unroll
        for (int nt = 0; nt < 8; ++nt)
            acc[mt][nt] = (floatx4){0.f, 0.f, 0.f, 0.f};

#pragma unroll
    for (int kt = 0; kt < 4; ++kt) {
        const int k0 = kt * 32;

        // A-frags: lane holds A[m=l16][k=k0+quad*8+j], j=0..7.
        // Per (mt,kt) the wave covers 16 full 128 B lines — coalesced.
        short8 afrag[2];
#pragma unroll
        for (int mt = 0; mt < 2; ++mt) {
            int row = rw0 + mt * 16 + l16;
            if (row >= M) row = M - 1;          // tail clamp (stores guarded)
            const float* ap = A + (size_t)row * DIM + k0 + quad * 8;
            const float4 x = *(const float4*)ap;
            const float4 y = *(const float4*)(ap + 4);
            unsigned p0 = (unsigned)f2bf(x.x) | ((unsigned)f2bf(x.y) << 16);
            unsigned p1 = (unsigned)f2bf(x.z) | ((unsigned)f2bf(x.w) << 16);
            unsigned p2 = (unsigned)f2bf(y.x) | ((unsigned)f2bf(y.y) << 16);
            unsigned p3 = (unsigned)f2bf(y.z) | ((unsigned)f2bf(y.w) << 16);
            uint4 packed = make_uint4(p0, p1, p2, p3);
            afrag[mt] = __builtin_bit_cast(short8, packed);
        }

        // B-frags from LDS: lane holds B[k=k0+quad*8+j][n=nt*16+l16]
#pragma unroll
        for (int nt = 0; nt < 8; ++nt) {
            const uint4 u = *(const uint4*)&sBt[(nt * 16 + l16) * BSTRIDE + k0 + quad * 8];
            const short8 bfrag = __builtin_bit_cast(short8, u);
#pragma unroll
            for (int mt = 0; mt < 2; ++mt)
                acc[mt][nt] = __builtin_amdgcn_mfma_f32_16x16x32_bf16(
                    afrag[mt], bfrag, acc[mt][nt], 0, 0, 0);
        }
    }

    // ---- PERMUTED store: C/D elem r of lane = (row quad*4+r, col 16nt+l16).
    // Row position p = l16*8+nt  =>  lane's 8 nt-values are 16 B contiguous
    // at byte offset l16*16; one dwordx4 per (mt,r); wave stores 4 rows/inst.
    uint4* G4 = (uint4*)G;
#pragma unroll
    for (int mt = 0; mt < 2; ++mt)
#pragma unroll
        for (int r = 0; r < 4; ++r) {
            const int row = rw0 + mt * 16 + quad * 4 + r;
            if (row < M) {
                unsigned p0 = (unsigned)f2bf(acc[mt][0][r]) | ((unsigned)f2bf(acc[mt][1][r]) << 16);
                unsigned p1 = (unsigned)f2bf(acc[mt][2][r]) | ((unsigned)f2bf(acc[mt][3][r]) << 16);
                unsigned p2 = (unsigned)f2bf(acc[mt][4][r]) | ((unsigned)f2bf(acc[mt][5][r]) << 16);
                unsigned p3 = (unsigned)f2bf(acc[mt][6][r]) | ((unsigned)f2bf(acc[mt][7][r]) << 16);
                G4[(size_t)row * 16 + l16] = make_uint4(p0, p1, p2, p3);
            }
        }
}

// ------------------------------------------------------- gather-mean-relu ---
// out[r,:] = relu( 1/25 * sum_s G[idx[r,s],:] ), G rows 256 B bf16 (permuted).
// 16-lane group per row; lane owns the 16 B chunk at offset l16*16, which in
// the permuted layout holds cols {16j + l16 : j=0..7}.
#define GRPB 32

__global__ __launch_bounds__(256, 4) void gather_mean_relu(
    const unsigned short* __restrict__ G,   // [n_nodes,128] bf16 permuted
    const int* __restrict__ idx,            // [n_rows,25]
    float* __restrict__ out,                // [n_rows,128] fp32
    int n_rows)
{
    __shared__ int sIdx[GRPB * DEG];

    const int tid  = threadIdx.x;
    const int row0 = blockIdx.x * GRPB;

    for (int i = tid; i < GRPB * DEG; i += 256)
        sIdx[i] = idx[(size_t)row0 * DEG + i];
    __syncthreads();

    const int grp = tid >> 4;   // 0..15
    const int l16 = tid & 15;   // which 16 B chunk of the 256 B row
    const uint4* G4 = (const uint4*)G;      // 16 uint4 per row

#pragma unroll
    for (int rr = 0; rr < 2; ++rr) {
        const int r = grp + rr * 16;

        uint4 v[DEG];
#pragma unroll
        for (int s = 0; s < DEG; ++s)
            v[s] = G4[(size_t)sIdx[r * DEG + s] * 16 + l16];

        float a0 = 0.f, a1 = 0.f, a2 = 0.f, a3 = 0.f;
        float a4 = 0.f, a5 = 0.f, a6 = 0.f, a7 = 0.f;
#pragma unroll
        for (int s = 0; s < DEG; ++s) {
            a0 += __uint_as_float(v[s].x << 16);
            a1 += __uint_as_float(v[s].x & 0xffff0000u);
            a2 += __uint_as_float(v[s].y << 16);
            a3 += __uint_as_float(v[s].y & 0xffff0000u);
            a4 += __uint_as_float(v[s].z << 16);
            a5 += __uint_as_float(v[s].z & 0xffff0000u);
            a6 += __uint_as_float(v[s].w << 16);
            a7 += __uint_as_float(v[s].w & 0xffff0000u);
        }
        const float inv = 1.0f / 25.0f;
        // a_j is col 16j + l16; for fixed j the 16 group-lanes write 16
        // consecutive fp32 => contiguous 64 B runs.
        float* orow = out + (size_t)(row0 + r) * DIM + l16;
        orow[0]   = fmaxf(a0 * inv, 0.f);
        orow[16]  = fmaxf(a1 * inv, 0.f);
        orow[32]  = fmaxf(a2 * inv, 0.f);
        orow[48]  = fmaxf(a3 * inv, 0.f);
        orow[64]  = fmaxf(a4 * inv, 0.f);
        orow[80]  = fmaxf(a5 * inv, 0.f);
        orow[96]  = fmaxf(a6 * inv, 0.f);
        orow[112] = fmaxf(a7 * inv, 0.f);
    }
}

// --------------------------------------------- fallback (round-2 kernel) ----
#define RPB 16
#define CG 32

__device__ __forceinline__ float4 relu4(float4 v) {
    return make_float4(fmaxf(v.x, 0.f), fmaxf(v.y, 0.f),
                       fmaxf(v.z, 0.f), fmaxf(v.w, 0.f));
}

__global__ __launch_bounds__(256, 4) void gcn_fused(
    const float* __restrict__ F, const int* __restrict__ idx,
    const float* __restrict__ W, float* __restrict__ out, int n_rows)
{
    __shared__ float4 sV[RPB * CG];
    __shared__ int    sIdx[RPB * DEG];

    const float4* F4 = (const float4*)F;
    const float4* W4 = (const float4*)W;
    float4* out4 = (float4*)out;

    const int tid = threadIdx.x;
    const int row0 = blockIdx.x * RPB;

    for (int i = tid; i < RPB * DEG; i += 256)
        sIdx[i] = idx[(size_t)row0 * DEG + i];
    __syncthreads();

    const int cg = tid & 31;
    const int rs = tid >> 5;

#pragma unroll
    for (int rr = 0; rr < 2; ++rr) {
        const int r = rs + rr * 8;
        int j[DEG];
#pragma unroll
        for (int s = 0; s < DEG; ++s) j[s] = sIdx[r * DEG + s];
        float4 acc = make_float4(0.f, 0.f, 0.f, 0.f);
#pragma unroll
        for (int s = 0; s < DEG; ++s) {
            float4 f = F4[(size_t)j[s] * CG + cg];
            acc.x += f.x; acc.y += f.y; acc.z += f.z; acc.w += f.w;
        }
        const float inv = 1.0f / 25.0f;
        acc.x *= inv; acc.y *= inv; acc.z *= inv; acc.w *= inv;
        sV[r * CG + cg] = acc;
    }
    __syncthreads();

    const float4* vA = &sV[rs * CG];
    const float4* vB = &sV[(rs + 8) * CG];
    float4 o0 = make_float4(0.f, 0.f, 0.f, 0.f);
    float4 o1 = make_float4(0.f, 0.f, 0.f, 0.f);
#pragma unroll 4
    for (int d4 = 0; d4 < CG; ++d4) {
        const float4 a = vA[d4];
        const float4 b = vB[d4];
        const float4 w0 = W4[(size_t)(4 * d4 + 0) * CG + cg];
        const float4 w1 = W4[(size_t)(4 * d4 + 1) * CG + cg];
        const float4 w2 = W4[(size_t)(4 * d4 + 2) * CG + cg];
        const float4 w3 = W4[(size_t)(4 * d4 + 3) * CG + cg];
        o0.x += a.x*w0.x + a.y*w1.x + a.z*w2.x + a.w*w3.x;
        o0.y += a.x*w0.y + a.y*w1.y + a.z*w2.y + a.w*w3.y;
        o0.z += a.x*w0.z + a.y*w1.z + a.z*w2.z + a.w*w3.z;
        o0.w += a.x*w0.w + a.y*w1.w + a.z*w2.w + a.w*w3.w;
        o1.x += b.x*w0.x + b.y*w1.x + b.z*w2.x + b.w*w3.x;
        o1.y += b.x*w0.y + b.y*w1.y + b.z*w2.y + b.w*w3.y;
        o1.z += b.x*w0.z + b.y*w1.z + b.z*w2.z + b.w*w3.z;
        o1.w += b.x*w0.w + b.y*w1.w + b.z*w2.w + b.w*w3.w;
    }
    out4[(size_t)(row0 + rs) * CG + cg]     = relu4(o0);
    out4[(size_t)(row0 + rs + 8) * CG + cg] = relu4(o1);
}

// ----------------------------------------------------------------------------
extern "C" void kernel_launch(void* const* d_in, const int* in_sizes, int n_in,
                              void* d_out, int out_size, void* d_ws, size_t ws_size,
                              hipStream_t stream) {
    const float* F   = (const float*)d_in[0];   // features [100000,128] fp32
    const int*   idx = (const int*)d_in[1];     // sample_res [8,4096,25] int32
    const float* W   = (const float*)d_in[2];   // weights [128,128] fp32
    float* out = (float*)d_out;                 // [8,4096,128] fp32

    const int n_nodes = in_sizes[0] / DIM;      // 100000
    const int n_rows  = in_sizes[1] / DEG;      // 32768

    const size_t need = (size_t)n_nodes * DIM * sizeof(unsigned short);
    if (ws_size >= need) {
        unsigned short* G = (unsigned short*)d_ws;
        gemm_fw<<<(n_nodes + 127) / 128, 256, 0, stream>>>(F, W, G, n_nodes);
        gather_mean_relu<<<n_rows / GRPB, 256, 0, stream>>>(G, idx, out, n_rows);
    } else {
        gcn_fused<<<n_rows / RPB, 256, 0, stream>>>(F, idx, W, out, n_rows);
    }
}